// Round 4
// baseline (38276.654 us; speedup 1.0000x reference)
//
#include <hip/hip_runtime.h>
#include <cstdint>
#include <cstddef>

// Problem constants (B, C, N, K from the reference)
#define BB_ 8
#define CC_ 128
#define NN_ 4096
#define KK_ 8

// ---- Scratch lives inside the out1 region (B*C*N*K = 33,554,432 floats). ----
// Viewed as 1024 slices ("bc" = b*128+c) of 32768 floats each:
//   bc 0        : xx   (dead after k_knn)
//   bc 1..8     : idx[b] bit-cast ints, idx[b][n][k] at IDX_OFF + b*32768 + n*8 + k
//   bc 9..136   : g[b][c][m] at G_OFF + (b*128+c)*4096 + m
// Write-once schedule: k_xx, k_knn, k_gemm write the scratch zones; k_out0 reads
// idx (writes out0 -> different buffer); k_gatherA writes bc 137..1023 (reads
// only bc 1..136); k_gatherB writes bc 0..136 recomputing g on the fly and
// pre-loading its own idx rows (its writes alias only its own rows' idx).
#define XX_OFF  0
#define IDX_OFF 32768
#define G_OFF   294912

__device__ __forceinline__ float lrelu(float v) { return v >= 0.f ? v : 0.01f * v; }

// Phase-A streaming insert, DESC-tie rule: on equal value the NEW element
// (larger m, since each thread's stream is ascending in m) ranks ABOVE equals.
template <int S>
__device__ __forceinline__ void insert_tieup(float (&v)[S], int (&ix)[S], float d, int m) {
  if (d < v[S - 1]) return;              // d == v[S-1] must insert (new above)
  bool bs[S];
#pragma unroll
  for (int s = 0; s < S; ++s) bs[s] = (v[s] > d);   // strict: equal -> new above
#pragma unroll
  for (int s = S - 1; s >= 1; --s) {
    v[s]  = bs[s] ? v[s]  : (bs[s - 1] ? d : v[s - 1]);
    ix[s] = bs[s] ? ix[s] : (bs[s - 1] ? m : ix[s - 1]);
  }
  if (!bs[0]) { v[0] = d; ix[0] = m; }
}

// Merge comparator emulating np.argsort(d)[..., ::-1][..., :k]:
// value DESC, on bitwise-equal values index DESC (reversed stable ascending).
template <int S>
__device__ __forceinline__ void insert_ti_desc(float (&v)[S], int (&ix)[S], float d, int m) {
  bool stay = (v[S - 1] > d) || (v[S - 1] == d && ix[S - 1] > m);
  if (stay) return;
  bool bs[S];
#pragma unroll
  for (int s = 0; s < S; ++s) bs[s] = (v[s] > d) || (v[s] == d && ix[s] > m);
#pragma unroll
  for (int s = S - 1; s >= 1; --s) {
    v[s]  = bs[s] ? v[s]  : (bs[s - 1] ? d : v[s - 1]);
    ix[s] = bs[s] ? ix[s] : (bs[s - 1] ? m : ix[s - 1]);
  }
  if (!bs[0]) { v[0] = d; ix[0] = m; }
}

// ---------------- K1: xx[b,n] = sum_c x^2 (numpy: rounded products, sequential adds).
__global__ void k_xx(const float* __restrict__ x, float* __restrict__ out1f) {
  int t = blockIdx.x * 256 + threadIdx.x;
  int b = t >> 12, n = t & (NN_ - 1);
  const float* p = x + ((size_t)b * CC_) * NN_ + n;
  float acc = 0.f;
  {
#pragma clang fp contract(off)
#pragma unroll
    for (int c = 0; c < CC_; ++c) {
      float v = p[(size_t)c * NN_];
      float v2 = v * v;
      acc = acc + v2;
    }
  }
  out1f[XX_OFF + t] = acc;
}

// ---------------- K2: fused pairwise-distance + top-8 per row (np-fp32 emulation).
// Identical numerics to the R3 version that passed the correctness check.
__global__ __launch_bounds__(256, 3) void k_knn(const float* __restrict__ x,
                                                float* __restrict__ out1f) {
  __shared__ __align__(16) float As[32][132];             // 16896 B
  __shared__ __align__(16) union MB {
    float B[64][132];                                     // 33792 B
    struct { float v[32 * 128]; int i[32 * 128]; } mg;    // merge scratch (aliased)
  } sb;
  __shared__ float xxm[64];

  const float* xxz = out1f + XX_OFF;
  int* idxz = (int*)(out1f + IDX_OFF);

  const int blk = blockIdx.x;
  const int b = blk >> 7;              // 128 row-tiles per batch
  const int n0 = (blk & 127) << 5;     // *32
  const float* xb = x + ((size_t)b * CC_) * NN_;
  const int t = threadIdx.x;
  const int tr = t & 15, tc = t >> 4;

  // Stage the 32 A-rows (n0..n0+31, all 128 c) once.
  {
    int r = t & 31, c0 = t >> 5;       // c0 in 0..7
    for (int c = c0; c < CC_; c += 8) As[r][c] = xb[(size_t)c * NN_ + n0 + r];
  }

  float xr[2];
#pragma unroll
  for (int i = 0; i < 2; ++i) xr[i] = xxz[(b << 12) + n0 + tr + 16 * i];

  float lv[2][8]; int li[2][8];
#pragma unroll
  for (int i = 0; i < 2; ++i)
#pragma unroll
    for (int s = 0; s < 8; ++s) { lv[i][s] = -INFINITY; li[i][s] = 0x7FFFFFFF; }

  for (int m0 = 0; m0 < NN_; m0 += 64) {
    __syncthreads();  // protect Bs/xxm from previous chunk's readers
    {
      int ml = t & 63, c1 = t >> 6;    // c1 in 0..3
      for (int c = c1; c < CC_; c += 4) sb.B[ml][c] = xb[(size_t)c * NN_ + m0 + ml];
      if (t < 64) xxm[t] = xxz[(b << 12) + m0 + t];
    }
    __syncthreads();

    float acc[2][4] = {};
#pragma unroll
    for (int cq = 0; cq < CC_; cq += 4) {
      float4 av[2], bv4[4];
#pragma unroll
      for (int i = 0; i < 2; ++i) av[i] = *reinterpret_cast<const float4*>(&As[tr + 16 * i][cq]);
#pragma unroll
      for (int j = 0; j < 4; ++j) bv4[j] = *reinterpret_cast<const float4*>(&sb.B[tc + 16 * j][cq]);
#pragma unroll
      for (int i = 0; i < 2; ++i)
#pragma unroll
        for (int j = 0; j < 4; ++j) {
          acc[i][j] = fmaf(av[i].x, bv4[j].x, acc[i][j]);
          acc[i][j] = fmaf(av[i].y, bv4[j].y, acc[i][j]);
          acc[i][j] = fmaf(av[i].z, bv4[j].z, acc[i][j]);
          acc[i][j] = fmaf(av[i].w, bv4[j].w, acc[i][j]);
        }
    }

    // Streaming selection (per-thread m-subset ascending; DESC-tie insert).
#pragma unroll
    for (int j = 0; j < 4; ++j) {
      float xm = xxm[tc + 16 * j];
      int m = m0 + tc + 16 * j;
#pragma unroll
      for (int i = 0; i < 2; ++i) {
        float d = (2.0f * acc[i][j] - xr[i]) - xm;
        insert_tieup<8>(lv[i], li[i], d, m);
      }
    }
  }

  // Merge: 16 tc-threads x 8 candidates per row -> exact top-8, ties index-desc.
  __syncthreads();
  float* candV = sb.mg.v;
  int*   candI = sb.mg.i;
#pragma unroll
  for (int i = 0; i < 2; ++i) {
    int r = tr + 16 * i;
#pragma unroll
    for (int s = 0; s < 8; ++s) {
      candV[(r << 7) + (tc << 3) + s] = lv[i][s];
      candI[(r << 7) + (tc << 3) + s] = li[i][s];
    }
  }
  __syncthreads();
  if (t < 32) {
    float bv[8]; int bi[8];
#pragma unroll
    for (int s = 0; s < 8; ++s) { bv[s] = -INFINITY; bi[s] = 0x7FFFFFFF; }
    for (int q = 0; q < 128; ++q) {
      insert_ti_desc<8>(bv, bi, candV[(t << 7) + q], candI[(t << 7) + q]);
    }
    int* op = idxz + (b << 15) + ((n0 + t) << 3);
#pragma unroll
    for (int q = 0; q < KK_; ++q) op[q] = bi[q];
  }
}

// ---------------- K3: g[b,o,m] = sum_c W2[o,c]*lrelu(x[b,c,m]) -> out1 G zone.
__global__ __launch_bounds__(256) void k_gemm(const float* __restrict__ x,
                                              const float* __restrict__ w2,
                                              float* __restrict__ out1f) {
  __shared__ __align__(16) float Ws[64][68];
  __shared__ __align__(16) float Fs[64][68];
  int bb = blockIdx.x >> 7;
  int r = blockIdx.x & 127;
  int o0 = (r >> 6) << 6;   // 0 or 64
  int m0 = (r & 63) << 6;
  const float* xb = x + ((size_t)bb * CC_) * NN_;
  float* gb = out1f + G_OFF + ((size_t)bb * CC_) * NN_;
  int t = threadIdx.x;
  int tm = t & 15, to = t >> 4;

  float acc[4][4] = {};
  for (int cc = 0; cc < CC_; cc += 64) {
    __syncthreads();
    {
      int cl = t & 63, q0 = t >> 6;   // q0 in 0..3
      for (int oo = q0; oo < 64; oo += 4) Ws[oo][cl] = w2[(o0 + oo) * CC_ + cc + cl];
      for (int c2 = q0; c2 < 64; c2 += 4) Fs[cl][c2] = lrelu(xb[(size_t)(cc + c2) * NN_ + m0 + cl]);
    }
    __syncthreads();
#pragma unroll
    for (int cq = 0; cq < 64; cq += 4) {
      float4 aw[4], bf[4];
#pragma unroll
      for (int i = 0; i < 4; ++i) aw[i] = *reinterpret_cast<const float4*>(&Ws[to + 16 * i][cq]);
#pragma unroll
      for (int j = 0; j < 4; ++j) bf[j] = *reinterpret_cast<const float4*>(&Fs[tm + 16 * j][cq]);
#pragma unroll
      for (int i = 0; i < 4; ++i)
#pragma unroll
        for (int j = 0; j < 4; ++j) {
          acc[i][j] = fmaf(aw[i].x, bf[j].x, acc[i][j]);
          acc[i][j] = fmaf(aw[i].y, bf[j].y, acc[i][j]);
          acc[i][j] = fmaf(aw[i].z, bf[j].z, acc[i][j]);
          acc[i][j] = fmaf(aw[i].w, bf[j].w, acc[i][j]);
        }
    }
  }
#pragma unroll
  for (int i = 0; i < 4; ++i)
#pragma unroll
    for (int j = 0; j < 4; ++j)
      gb[((size_t)(o0 + to + 16 * i)) * NN_ + m0 + tm + 16 * j] = acc[i][j];
}

// ---------------- K4: out0[b,c,n] = x + (sum_k lrelu(x[.,idx_k]) + lrelu(self))/9.
// Reads idx from out1 scratch, writes out0 (different buffer -> no hazards).
__global__ void k_out0(const float* __restrict__ x, const float* __restrict__ out1f,
                       float* __restrict__ out) {
  __shared__ int idxL[512];   // 64 n * 8 k
  int b = blockIdx.x >> 6, nt = blockIdx.x & 63;
  int n0 = nt << 6;
  int t = threadIdx.x;
  const int* ib = (const int*)(out1f + IDX_OFF) + (b << 15) + (n0 << 3);
  idxL[t] = ib[t];
  idxL[t + 256] = ib[t + 256];
  __syncthreads();
  int nl = t & 63, c0 = t >> 6;
  for (int c = c0; c < CC_; c += 4) {
    const float* row = x + ((size_t)b * CC_ + c) * NN_;
    float self = row[n0 + nl];
    float s = 0.f;
#pragma unroll
    for (int k = 0; k < KK_; ++k) s += lrelu(row[idxL[(nl << 3) + k]]);
    s += lrelu(self);   // reference feats order: 8 grouped then center
    out[((size_t)b * CC_ + c) * NN_ + n0 + nl] = fmaf(s, 1.0f / 9.0f, self);
  }
}

// ---------------- K5: gather for bc = 137..1023 (b=1 c>=9 and b=2..7 all c).
// Reads only scratch slices bc 1..136; writes bc >= 137 -> disjoint, safe.
__global__ void k_gatherA(float* __restrict__ out1f) {
  int bc = 137 + blockIdx.x;
  int b = bc >> 7;
  const int* idxz = (const int*)(out1f + IDX_OFF) + (b << 15);
  const float* gs = out1f + G_OFF + (size_t)bc * (size_t)NN_;
  float* op = out1f + (size_t)bc * 32768;
  for (int e = threadIdx.x; e < 32768; e += 256) {
    op[e] = gs[idxz[e]];
  }
}

// ---------------- K6: produce bc = 0..136 (b=0 all c; b=1 c<=8), overwriting the
// scratch zones. Recomputes g-columns on the fly (no g reads). Pre-loads its own
// 512 idx entries (rows 32T..32T+31 for b=0,1) into LDS before any global write;
// its writes alias only idx entries of its OWN rows, so no cross-block hazard.
__global__ __launch_bounds__(256) void k_gatherB(const float* __restrict__ x,
                                                 const float* __restrict__ w2,
                                                 float* __restrict__ out1f) {
  __shared__ int idxL[512];          // col = bsel*256 + r*8 + k
  __shared__ float xcols[8][128];
  int T = blockIdx.x;                // rows 32T .. 32T+31
  int t = threadIdx.x;
  const int* idxz = (const int*)(out1f + IDX_OFF);
  idxL[t]       = idxz[0 * 32768 + ((T * 32) << 3) + t];
  idxL[t + 256] = idxz[1 * 32768 + ((T * 32) << 3) + t];
  __syncthreads();                   // all idx preloaded before ANY write

  for (int it = 0; it < 64; ++it) {
    int colbase = it * 8;
    {  // load phase: 32 threads per column, 8 columns
      int cg = t >> 5, lane = t & 31;
      int col = colbase + cg;
      int bsel = col >> 8;
      int m = idxL[col];
      const float* xb = x + ((size_t)bsel * CC_) * NN_;
#pragma unroll
      for (int q = 0; q < 4; ++q) {
        int c = lane + 32 * q;
        xcols[cg][c] = lrelu(xb[(size_t)c * NN_ + m]);
      }
    }
    __syncthreads();
    {  // compute phase: thread (cg, c0) does channels c0+32h of column cg
      int cg = t >> 5, c0 = t & 31;
      int col = colbase + cg;
      int bsel = col >> 8;
      int rk = col & 255;
      int n = T * 32 + (rk >> 3);
      int k = rk & 7;
      int hmax = (bsel == 0) ? 4 : 1;
      for (int h = 0; h < hmax; ++h) {
        int c = c0 + 32 * h;
        const float* wr = w2 + c * CC_;
        float acc = 0.f;
#pragma unroll 8
        for (int cc = 0; cc < CC_; ++cc) acc = fmaf(wr[cc], xcols[cg][cc], acc);
        if (bsel == 0 || c <= 8) {
          out1f[(size_t)(bsel * CC_ + c) * 32768 + (n << 3) + k] = acc;
        }
      }
    }
    __syncthreads();
  }
}

extern "C" void kernel_launch(void* const* d_in, const int* in_sizes, int n_in,
                              void* d_out, int out_size, void* d_ws, size_t ws_size,
                              hipStream_t stream) {
  const float* x  = (const float*)d_in[0];
  // d_in[1] (W) is mathematically irrelevant: mean(softmax, axis=2) == 1/9 exactly.
  const float* w2 = (const float*)d_in[2];

  float* out0  = (float*)d_out;
  float* out1f = out0 + (size_t)BB_ * CC_ * NN_;
  (void)d_ws; (void)ws_size;   // zero-workspace design: ws_size may be anything

  k_xx     <<<(BB_ * NN_) / 256,  256, 0, stream>>>(x, out1f);
  k_knn    <<<BB_ * (NN_ / 32),   256, 0, stream>>>(x, out1f);
  k_gemm   <<<BB_ * 128,          256, 0, stream>>>(x, w2, out1f);
  k_out0   <<<BB_ * 64,           256, 0, stream>>>(x, out1f, out0);
  k_gatherA<<<1024 - 137,         256, 0, stream>>>(out1f);
  k_gatherB<<<128,                256, 0, stream>>>(x, w2, out1f);
}

// Round 5
// 2344.068 us; speedup vs baseline: 16.3292x; 16.3292x over previous
//
#include <hip/hip_runtime.h>
#include <cstdint>
#include <cstddef>

// Problem constants (B, C, N, K from the reference)
#define BB_ 8
#define CC_ 128
#define NN_ 4096
#define KK_ 8

// ---- Scratch lives inside the out1 region (B*C*N*K = 33,554,432 floats). ----
// Viewed as 1024 slices ("bc" = b*128+c) of 32768 floats each:
//   bc 0        : xx   (dead after k_knn)
//   bc 1..8     : idx[b] bit-cast ints, idx[b][n][k] at IDX_OFF + b*32768 + n*8 + k
//   bc 9..136   : g[b][c][m] at G_OFF + (b*128+c)*4096 + m
// Write-once schedule: k_xx, k_knn, k_gemm write the scratch zones; k_out0 reads
// idx (writes out0 -> different buffer); k_gatherA writes bc 137..1023 (reads
// only bc 1..136); k_gatherB writes bc 0..136 recomputing g on the fly and
// pre-loading its own idx rows (its writes alias only its own rows' idx).
#define XX_OFF  0
#define IDX_OFF 32768
#define G_OFF   294912

__device__ __forceinline__ float lrelu(float v) { return v >= 0.f ? v : 0.01f * v; }

// Phase-A streaming insert, DESC-tie rule: on equal value the NEW element
// (larger m, since each thread's stream is ascending in m) ranks ABOVE equals.
template <int S>
__device__ __forceinline__ void insert_tieup(float (&v)[S], int (&ix)[S], float d, int m) {
  if (d < v[S - 1]) return;              // d == v[S-1] must insert (new above)
  bool bs[S];
#pragma unroll
  for (int s = 0; s < S; ++s) bs[s] = (v[s] > d);   // strict: equal -> new above
#pragma unroll
  for (int s = S - 1; s >= 1; --s) {
    v[s]  = bs[s] ? v[s]  : (bs[s - 1] ? d : v[s - 1]);
    ix[s] = bs[s] ? ix[s] : (bs[s - 1] ? m : ix[s - 1]);
  }
  if (!bs[0]) { v[0] = d; ix[0] = m; }
}

// Merge comparator emulating np.argsort(d)[..., ::-1][..., :k]:
// value DESC, on bitwise-equal values index DESC (reversed stable ascending).
template <int S>
__device__ __forceinline__ void insert_ti_desc(float (&v)[S], int (&ix)[S], float d, int m) {
  bool stay = (v[S - 1] > d) || (v[S - 1] == d && ix[S - 1] > m);
  if (stay) return;
  bool bs[S];
#pragma unroll
  for (int s = 0; s < S; ++s) bs[s] = (v[s] > d) || (v[s] == d && ix[s] > m);
#pragma unroll
  for (int s = S - 1; s >= 1; --s) {
    v[s]  = bs[s] ? v[s]  : (bs[s - 1] ? d : v[s - 1]);
    ix[s] = bs[s] ? ix[s] : (bs[s - 1] ? m : ix[s - 1]);
  }
  if (!bs[0]) { v[0] = d; ix[0] = m; }
}

// ---------------- K1: xx[b,n] = sum_c x^2 (numpy: rounded products, sequential adds).
__global__ void k_xx(const float* __restrict__ x, float* __restrict__ out1f) {
  int t = blockIdx.x * 256 + threadIdx.x;
  int b = t >> 12, n = t & (NN_ - 1);
  const float* p = x + ((size_t)b * CC_) * NN_ + n;
  float acc = 0.f;
  {
#pragma clang fp contract(off)
#pragma unroll
    for (int c = 0; c < CC_; ++c) {
      float v = p[(size_t)c * NN_];
      float v2 = v * v;
      acc = acc + v2;
    }
  }
  out1f[XX_OFF + t] = acc;
}

// ---------------- K2: fused pairwise-distance + top-8 per row (np-fp32 emulation).
// Numerics identical to the R3/R4 version that passed. Register-pressure fix:
// unroll-8 inner loop (was full 32 -> ~48 live float4s -> allocator spilled the
// long-lived lv/li top-8 arrays to scratch: 94 GB of spill traffic, 34 ms) and
// launch_bounds(256,2) (VGPR budget 256; LDS=51200B still allows 3 blocks/CU).
__global__ __launch_bounds__(256, 2) void k_knn(const float* __restrict__ x,
                                                float* __restrict__ out1f) {
  __shared__ __align__(16) float As[32][132];             // 16896 B
  __shared__ __align__(16) union MB {
    float B[64][132];                                     // 33792 B
    struct { float v[32 * 128]; int i[32 * 128]; } mg;    // merge scratch (aliased)
  } sb;
  __shared__ float xxm[64];

  const float* xxz = out1f + XX_OFF;
  int* idxz = (int*)(out1f + IDX_OFF);

  const int blk = blockIdx.x;
  const int b = blk >> 7;              // 128 row-tiles per batch
  const int n0 = (blk & 127) << 5;     // *32
  const float* xb = x + ((size_t)b * CC_) * NN_;
  const int t = threadIdx.x;
  const int tr = t & 15, tc = t >> 4;

  // Stage the 32 A-rows (n0..n0+31, all 128 c) once.
  {
    int r = t & 31, c0 = t >> 5;       // c0 in 0..7
    for (int c = c0; c < CC_; c += 8) As[r][c] = xb[(size_t)c * NN_ + n0 + r];
  }

  float xr[2];
#pragma unroll
  for (int i = 0; i < 2; ++i) xr[i] = xxz[(b << 12) + n0 + tr + 16 * i];

  float lv[2][8]; int li[2][8];
#pragma unroll
  for (int i = 0; i < 2; ++i)
#pragma unroll
    for (int s = 0; s < 8; ++s) { lv[i][s] = -INFINITY; li[i][s] = 0x7FFFFFFF; }

  for (int m0 = 0; m0 < NN_; m0 += 64) {
    __syncthreads();  // protect Bs/xxm from previous chunk's readers
    {
      int ml = t & 63, c1 = t >> 6;    // c1 in 0..3
      for (int c = c1; c < CC_; c += 4) sb.B[ml][c] = xb[(size_t)c * NN_ + m0 + ml];
      if (t < 64) xxm[t] = xxz[(b << 12) + m0 + t];
    }
    __syncthreads();

    float acc[2][4] = {};
#pragma unroll 8
    for (int cq = 0; cq < CC_; cq += 4) {
      float4 av[2], bv4[4];
#pragma unroll
      for (int i = 0; i < 2; ++i) av[i] = *reinterpret_cast<const float4*>(&As[tr + 16 * i][cq]);
#pragma unroll
      for (int j = 0; j < 4; ++j) bv4[j] = *reinterpret_cast<const float4*>(&sb.B[tc + 16 * j][cq]);
#pragma unroll
      for (int i = 0; i < 2; ++i)
#pragma unroll
        for (int j = 0; j < 4; ++j) {
          acc[i][j] = fmaf(av[i].x, bv4[j].x, acc[i][j]);
          acc[i][j] = fmaf(av[i].y, bv4[j].y, acc[i][j]);
          acc[i][j] = fmaf(av[i].z, bv4[j].z, acc[i][j]);
          acc[i][j] = fmaf(av[i].w, bv4[j].w, acc[i][j]);
        }
    }

    // Streaming selection (per-thread m-subset ascending; DESC-tie insert).
#pragma unroll
    for (int j = 0; j < 4; ++j) {
      float xm = xxm[tc + 16 * j];
      int m = m0 + tc + 16 * j;
#pragma unroll
      for (int i = 0; i < 2; ++i) {
        float d = (2.0f * acc[i][j] - xr[i]) - xm;
        insert_tieup<8>(lv[i], li[i], d, m);
      }
    }
  }

  // Merge: 16 tc-threads x 8 candidates per row -> exact top-8, ties index-desc.
  __syncthreads();
  float* candV = sb.mg.v;
  int*   candI = sb.mg.i;
#pragma unroll
  for (int i = 0; i < 2; ++i) {
    int r = tr + 16 * i;
#pragma unroll
    for (int s = 0; s < 8; ++s) {
      candV[(r << 7) + (tc << 3) + s] = lv[i][s];
      candI[(r << 7) + (tc << 3) + s] = li[i][s];
    }
  }
  __syncthreads();
  if (t < 32) {
    float bv[8]; int bi[8];
#pragma unroll
    for (int s = 0; s < 8; ++s) { bv[s] = -INFINITY; bi[s] = 0x7FFFFFFF; }
    for (int q = 0; q < 128; ++q) {
      insert_ti_desc<8>(bv, bi, candV[(t << 7) + q], candI[(t << 7) + q]);
    }
    int* op = idxz + (b << 15) + ((n0 + t) << 3);
#pragma unroll
    for (int q = 0; q < KK_; ++q) op[q] = bi[q];
  }
}

// ---------------- K3: g[b,o,m] = sum_c W2[o,c]*lrelu(x[b,c,m]) -> out1 G zone.
__global__ __launch_bounds__(256) void k_gemm(const float* __restrict__ x,
                                              const float* __restrict__ w2,
                                              float* __restrict__ out1f) {
  __shared__ __align__(16) float Ws[64][68];
  __shared__ __align__(16) float Fs[64][68];
  int bb = blockIdx.x >> 7;
  int r = blockIdx.x & 127;
  int o0 = (r >> 6) << 6;   // 0 or 64
  int m0 = (r & 63) << 6;
  const float* xb = x + ((size_t)bb * CC_) * NN_;
  float* gb = out1f + G_OFF + ((size_t)bb * CC_) * NN_;
  int t = threadIdx.x;
  int tm = t & 15, to = t >> 4;

  float acc[4][4] = {};
  for (int cc = 0; cc < CC_; cc += 64) {
    __syncthreads();
    {
      int cl = t & 63, q0 = t >> 6;   // q0 in 0..3
      for (int oo = q0; oo < 64; oo += 4) Ws[oo][cl] = w2[(o0 + oo) * CC_ + cc + cl];
      for (int c2 = q0; c2 < 64; c2 += 4) Fs[cl][c2] = lrelu(xb[(size_t)(cc + c2) * NN_ + m0 + cl]);
    }
    __syncthreads();
#pragma unroll 8
    for (int cq = 0; cq < 64; cq += 4) {
      float4 aw[4], bf[4];
#pragma unroll
      for (int i = 0; i < 4; ++i) aw[i] = *reinterpret_cast<const float4*>(&Ws[to + 16 * i][cq]);
#pragma unroll
      for (int j = 0; j < 4; ++j) bf[j] = *reinterpret_cast<const float4*>(&Fs[tm + 16 * j][cq]);
#pragma unroll
      for (int i = 0; i < 4; ++i)
#pragma unroll
        for (int j = 0; j < 4; ++j) {
          acc[i][j] = fmaf(aw[i].x, bf[j].x, acc[i][j]);
          acc[i][j] = fmaf(aw[i].y, bf[j].y, acc[i][j]);
          acc[i][j] = fmaf(aw[i].z, bf[j].z, acc[i][j]);
          acc[i][j] = fmaf(aw[i].w, bf[j].w, acc[i][j]);
        }
    }
  }
#pragma unroll
  for (int i = 0; i < 4; ++i)
#pragma unroll
    for (int j = 0; j < 4; ++j)
      gb[((size_t)(o0 + to + 16 * i)) * NN_ + m0 + tm + 16 * j] = acc[i][j];
}

// ---------------- K4: out0[b,c,n] = x + (sum_k lrelu(x[.,idx_k]) + lrelu(self))/9.
// Reads idx from out1 scratch, writes out0 (different buffer -> no hazards).
__global__ void k_out0(const float* __restrict__ x, const float* __restrict__ out1f,
                       float* __restrict__ out) {
  __shared__ int idxL[512];   // 64 n * 8 k
  int b = blockIdx.x >> 6, nt = blockIdx.x & 63;
  int n0 = nt << 6;
  int t = threadIdx.x;
  const int* ib = (const int*)(out1f + IDX_OFF) + (b << 15) + (n0 << 3);
  idxL[t] = ib[t];
  idxL[t + 256] = ib[t + 256];
  __syncthreads();
  int nl = t & 63, c0 = t >> 6;
  for (int c = c0; c < CC_; c += 4) {
    const float* row = x + ((size_t)b * CC_ + c) * NN_;
    float self = row[n0 + nl];
    float s = 0.f;
#pragma unroll
    for (int k = 0; k < KK_; ++k) s += lrelu(row[idxL[(nl << 3) + k]]);
    s += lrelu(self);   // reference feats order: 8 grouped then center
    out[((size_t)b * CC_ + c) * NN_ + n0 + nl] = fmaf(s, 1.0f / 9.0f, self);
  }
}

// ---------------- K5: gather for bc = 137..1023 (b=1 c>=9 and b=2..7 all c).
// Reads only scratch slices bc 1..136; writes bc >= 137 -> disjoint, safe.
__global__ void k_gatherA(float* __restrict__ out1f) {
  int bc = 137 + blockIdx.x;
  int b = bc >> 7;
  const int* idxz = (const int*)(out1f + IDX_OFF) + (b << 15);
  const float* gs = out1f + G_OFF + (size_t)bc * (size_t)NN_;
  float* op = out1f + (size_t)bc * 32768;
  for (int e = threadIdx.x; e < 32768; e += 256) {
    op[e] = gs[idxz[e]];
  }
}

// ---------------- K6: produce bc = 0..136 (b=0 all c; b=1 c<=8), overwriting the
// scratch zones. Recomputes g-columns on the fly (no g reads). Pre-loads its own
// 512 idx entries (rows 32T..32T+31 for b=0,1) into LDS before any global write;
// its writes alias only idx entries of its OWN rows, so no cross-block hazard.
__global__ __launch_bounds__(256) void k_gatherB(const float* __restrict__ x,
                                                 const float* __restrict__ w2,
                                                 float* __restrict__ out1f) {
  __shared__ int idxL[512];          // col = bsel*256 + r*8 + k
  __shared__ float xcols[8][128];
  int T = blockIdx.x;                // rows 32T .. 32T+31
  int t = threadIdx.x;
  const int* idxz = (const int*)(out1f + IDX_OFF);
  idxL[t]       = idxz[0 * 32768 + ((T * 32) << 3) + t];
  idxL[t + 256] = idxz[1 * 32768 + ((T * 32) << 3) + t];
  __syncthreads();                   // all idx preloaded before ANY write

  for (int it = 0; it < 64; ++it) {
    int colbase = it * 8;
    {  // load phase: 32 threads per column, 8 columns
      int cg = t >> 5, lane = t & 31;
      int col = colbase + cg;
      int bsel = col >> 8;
      int m = idxL[col];
      const float* xb = x + ((size_t)bsel * CC_) * NN_;
#pragma unroll
      for (int q = 0; q < 4; ++q) {
        int c = lane + 32 * q;
        xcols[cg][c] = lrelu(xb[(size_t)c * NN_ + m]);
      }
    }
    __syncthreads();
    {  // compute phase: thread (cg, c0) does channels c0+32h of column cg
      int cg = t >> 5, c0 = t & 31;
      int col = colbase + cg;
      int bsel = col >> 8;
      int rk = col & 255;
      int n = T * 32 + (rk >> 3);
      int k = rk & 7;
      int hmax = (bsel == 0) ? 4 : 1;
      for (int h = 0; h < hmax; ++h) {
        int c = c0 + 32 * h;
        const float* wr = w2 + c * CC_;
        float acc = 0.f;
#pragma unroll 8
        for (int cc = 0; cc < CC_; ++cc) acc = fmaf(wr[cc], xcols[cg][cc], acc);
        if (bsel == 0 || c <= 8) {
          out1f[(size_t)(bsel * CC_ + c) * 32768 + (n << 3) + k] = acc;
        }
      }
    }
    __syncthreads();
  }
}

extern "C" void kernel_launch(void* const* d_in, const int* in_sizes, int n_in,
                              void* d_out, int out_size, void* d_ws, size_t ws_size,
                              hipStream_t stream) {
  const float* x  = (const float*)d_in[0];
  // d_in[1] (W) is mathematically irrelevant: mean(softmax, axis=2) == 1/9 exactly.
  const float* w2 = (const float*)d_in[2];

  float* out0  = (float*)d_out;
  float* out1f = out0 + (size_t)BB_ * CC_ * NN_;
  (void)d_ws; (void)ws_size;   // zero-workspace design: ws_size may be anything

  k_xx     <<<(BB_ * NN_) / 256,  256, 0, stream>>>(x, out1f);
  k_knn    <<<BB_ * (NN_ / 32),   256, 0, stream>>>(x, out1f);
  k_gemm   <<<BB_ * 128,          256, 0, stream>>>(x, w2, out1f);
  k_out0   <<<BB_ * 64,           256, 0, stream>>>(x, out1f, out0);
  k_gatherA<<<1024 - 137,         256, 0, stream>>>(out1f);
  k_gatherB<<<128,                256, 0, stream>>>(x, w2, out1f);
}